// Round 17
// baseline (176.429 us; speedup 1.0000x reference)
//
#include <hip/hip_runtime.h>
#include <hip/hip_bf16.h>

#define D_    1024
#define H_    16
#define HD_   64
#define RANK_ 256
#define B_    4
#define N_    2048

typedef __attribute__((ext_vector_type(8))) short bf16x8;
typedef __attribute__((ext_vector_type(4))) float f32x4;
typedef __attribute__((ext_vector_type(16))) float f32x16;
typedef __attribute__((ext_vector_type(8))) unsigned short u16x8;

__device__ __forceinline__ unsigned short f2bf(float f) {
  unsigned int u = __float_as_uint(f);
  u += 0x7FFF + ((u >> 16) & 1);   // round-to-nearest-even
  return (unsigned short)(u >> 16);
}

__device__ __forceinline__ unsigned int pk2(float a, float b) {
  float2 t; t.x = a; t.y = b;
  __hip_bfloat162 h = __float22bfloat162_rn(t);
  union { __hip_bfloat162 h; unsigned int u; } cv; cv.h = h; return cv.u;
}

// raw v_exp_f32 (2^x): args bounded, skip the OCML range-checked routine
__device__ __forceinline__ float fexp2(float x) {
#if __has_builtin(__builtin_amdgcn_exp2f)
  return __builtin_amdgcn_exp2f(x);
#else
  return exp2f(x);
#endif
}

__device__ __forceinline__ void gl_lds16(const void* g, void* l) {
  __builtin_amdgcn_global_load_lds(
      (const __attribute__((address_space(1))) unsigned int*)g,
      (__attribute__((address_space(3))) unsigned int*)l,
      16, 0, 0);
}

// ---------------- fused fp32 -> bf16 convert: x + 5 weight matrices ----------------
// float4 segments: x 2097152 | Wq 262144 | Wd 65536 | Wk 65536 | Wv 65536 | Wo 262144
__global__ __launch_bounds__(256)
void k_cvt_all(const float* __restrict__ x,
               const float* __restrict__ w0, const float* __restrict__ w1,
               const float* __restrict__ w2, const float* __restrict__ w3,
               const float* __restrict__ w4,
               unsigned short* __restrict__ ox,
               unsigned short* __restrict__ o0, unsigned short* __restrict__ o1,
               unsigned short* __restrict__ o2, unsigned short* __restrict__ o3,
               unsigned short* __restrict__ o4) {
  int i = blockIdx.x * 256 + threadIdx.x;
  const float* in; unsigned short* out; int off;
  if (i < 2097152)      { in = x;  out = ox; off = i; }
  else if (i < 2359296) { in = w0; out = o0; off = i - 2097152; }
  else if (i < 2424832) { in = w1; out = o1; off = i - 2359296; }
  else if (i < 2490368) { in = w2; out = o2; off = i - 2424832; }
  else if (i < 2555904) { in = w3; out = o3; off = i - 2490368; }
  else                  { in = w4; out = o4; off = i - 2555904; }
  float4 v = ((const float4*)in)[off];
  union { unsigned short s[4]; unsigned long long u; } r;
  r.s[0] = f2bf(v.x); r.s[1] = f2bf(v.y); r.s[2] = f2bf(v.z); r.s[3] = f2bf(v.w);
  ((unsigned long long*)out)[off] = r.u;
}

// ---------------- GEMM: C[M,N] = (A[M,K] * W[N,K]^T + bias) * scale ----------------
// 8 waves (512 thr), 128x128 tile, per-wave 64x32 output (wm=wid>>2, wn=wid&3).
// BK=64, XOR-swizzled LDS, bijective XCD-swizzled 1-D grid (gridDim.x % 8 == 0).
__device__ __forceinline__ void storeC(float* C, size_t idx, float v) { C[idx] = v; }
__device__ __forceinline__ void storeC(unsigned short* C, size_t idx, float v) { C[idx] = f2bf(v); }

template<typename OUT_T, bool BROW>
__global__ __launch_bounds__(512)
void k_gemm_bt(const unsigned short* __restrict__ A,
               const unsigned short* __restrict__ Bw,
               const float* __restrict__ bias,
               OUT_T* __restrict__ C,
               int M, int N, int K, float scale, int nx) {
  __shared__ unsigned short As[128 * 64];
  __shared__ unsigned short Bs[128 * 64];
  const int tid  = threadIdx.x;
  const int lane = tid & 63;
  const int wid  = tid >> 6;
  const int wm   = wid >> 2;
  const int wn   = wid & 3;

  const int nb    = gridDim.x;
  const int chunk = nb >> 3;
  const int l     = (blockIdx.x & 7) * chunk + (blockIdx.x >> 3);
  const int n0    = (l % nx) * 128;
  const int m0    = (l / nx) * 128;

  f32x4 acc[4][2] = {};

  const int prow = tid >> 3;
  const int pblk = (tid & 7) ^ (prow & 7);
  const int le   = tid * 8;

  const int g = lane >> 4;
  const int m = lane & 15;
  const int s7 = lane & 7;

  for (int kt = 0; kt < K; kt += 64) {
#pragma unroll
    for (int p = 0; p < 2; ++p)
      gl_lds16(A  + (size_t)(m0 + p * 64 + prow) * K + kt + pblk * 8, &As[p * 4096 + le]);
#pragma unroll
    for (int p = 0; p < 2; ++p)
      gl_lds16(Bw + (size_t)(n0 + p * 64 + prow) * K + kt + pblk * 8, &Bs[p * 4096 + le]);
    __syncthreads();

#pragma unroll
    for (int c = 0; c < 2; ++c) {
      const int blk = (c * 4 + g) ^ s7;
      bf16x8 af[4], bfr[2];
#pragma unroll
      for (int i = 0; i < 4; ++i) {
        const int row = wm * 64 + i * 16 + m;
        af[i] = *(const bf16x8*)&As[row * 64 + blk * 8];
      }
#pragma unroll
      for (int j = 0; j < 2; ++j) {
        const int row = wn * 32 + j * 16 + m;
        bfr[j] = *(const bf16x8*)&Bs[row * 64 + blk * 8];
      }
#pragma unroll
      for (int i = 0; i < 4; ++i)
#pragma unroll
        for (int j = 0; j < 2; ++j)
          acc[i][j] = __builtin_amdgcn_mfma_f32_16x16x32_bf16(af[i], bfr[j], acc[i][j], 0, 0, 0);
    }
    __syncthreads();
  }

  const int r0 = m0 + wm * 64 + ((lane >> 4) * 4);
  const int c0 = n0 + wn * 32 + m;
  if constexpr (BROW) {
#pragma unroll
    for (int i = 0; i < 4; ++i)
#pragma unroll
      for (int r = 0; r < 4; ++r) {
        float br = bias[r0 + i * 16 + r];
#pragma unroll
        for (int j = 0; j < 2; ++j) {
          float v = (acc[i][j][r] + br) * scale;
          storeC(C, (size_t)(r0 + i * 16 + r) * N + (c0 + j * 16), v);
        }
      }
  } else {
#pragma unroll
    for (int j = 0; j < 2; ++j) {
      float bj = bias[c0 + j * 16];
#pragma unroll
      for (int i = 0; i < 4; ++i)
#pragma unroll
        for (int r = 0; r < 4; ++r) {
          float v = (acc[i][j][r] + bj) * scale;
          storeC(C, (size_t)(r0 + i * 16 + r) * N + (c0 + j * 16), v);
        }
    }
  }
}

// ---------------- fused q+kv GEMM: [q | kv_latent] = x @ [Wq ; Wd]^T ----------------
__global__ __launch_bounds__(512)
void k_gemm_qkv(const unsigned short* __restrict__ A,
                const unsigned short* __restrict__ Wq,
                const unsigned short* __restrict__ Wd,
                const float* __restrict__ bq,
                const float* __restrict__ bd,
                unsigned short* __restrict__ Cq,
                unsigned short* __restrict__ Ckv,
                float cs) {
  __shared__ unsigned short As[128 * 64];
  __shared__ unsigned short Bs[128 * 64];
  const int K = 1024;
  const int tid  = threadIdx.x;
  const int lane = tid & 63;
  const int wid  = tid >> 6;
  const int wm   = wid >> 2;
  const int wn   = wid & 3;

  const int chunk = gridDim.x >> 3;            // 80
  const int l     = (blockIdx.x & 7) * chunk + (blockIdx.x >> 3);
  const int n0    = (l % 10) * 128;
  const int m0    = (l / 10) * 128;

  const bool isQ = (n0 < 1024);
  const unsigned short* Bw = isQ ? Wq : Wd;
  const float* bias        = isQ ? bq : bd;
  unsigned short* C        = isQ ? Cq : Ckv;
  const float scale        = isQ ? cs : 1.0f;
  const int Nout           = isQ ? 1024 : 256;
  const int nb0            = isQ ? n0 : n0 - 1024;

  f32x4 acc[4][2] = {};

  const int prow = tid >> 3;
  const int pblk = (tid & 7) ^ (prow & 7);
  const int le   = tid * 8;

  const int g = lane >> 4;
  const int m = lane & 15;
  const int s7 = lane & 7;

  for (int kt = 0; kt < K; kt += 64) {
#pragma unroll
    for (int p = 0; p < 2; ++p)
      gl_lds16(A  + (size_t)(m0 + p * 64 + prow) * K + kt + pblk * 8, &As[p * 4096 + le]);
#pragma unroll
    for (int p = 0; p < 2; ++p)
      gl_lds16(Bw + (size_t)(nb0 + p * 64 + prow) * K + kt + pblk * 8, &Bs[p * 4096 + le]);
    __syncthreads();

#pragma unroll
    for (int c = 0; c < 2; ++c) {
      const int blk = (c * 4 + g) ^ s7;
      bf16x8 af[4], bfr[2];
#pragma unroll
      for (int i = 0; i < 4; ++i) {
        const int row = wm * 64 + i * 16 + m;
        af[i] = *(const bf16x8*)&As[row * 64 + blk * 8];
      }
#pragma unroll
      for (int j = 0; j < 2; ++j) {
        const int row = wn * 32 + j * 16 + m;
        bfr[j] = *(const bf16x8*)&Bs[row * 64 + blk * 8];
      }
#pragma unroll
      for (int i = 0; i < 4; ++i)
#pragma unroll
        for (int j = 0; j < 2; ++j)
          acc[i][j] = __builtin_amdgcn_mfma_f32_16x16x32_bf16(af[i], bfr[j], acc[i][j], 0, 0, 0);
    }
    __syncthreads();
  }

  const int r0 = m0 + wm * 64 + ((lane >> 4) * 4);
  const int c0 = nb0 + wn * 32 + m;
#pragma unroll
  for (int j = 0; j < 2; ++j) {
    float bj = bias[c0 + j * 16];
#pragma unroll
    for (int i = 0; i < 4; ++i)
#pragma unroll
      for (int r = 0; r < 4; ++r) {
        float v = (acc[i][j][r] + bj) * scale;
        C[(size_t)(r0 + i * 16 + r) * Nout + (c0 + j * 16)] = f2bf(v);
      }
  }
}

// ---------------- fused k + v^T GEMM (both K=256 from kv_latent) ----------------
// 1024 blocks: logical 0-511 -> k = kv @ Wk^T + bk (col-bias, C [8192,1024]);
// 512-1023 -> v^T = Wv @ kv^T + bv (row-bias, C [1024,8192]).
// Per-block-uniform select; XCD swizzle over the combined grid (chunk 128).
__global__ __launch_bounds__(512)
void k_gemm_kv(const unsigned short* __restrict__ kv,
               const unsigned short* __restrict__ Wk,
               const float* __restrict__ bk,
               unsigned short* __restrict__ Ck,
               const unsigned short* __restrict__ Wv,
               const float* __restrict__ bv,
               unsigned short* __restrict__ Cvt) {
  __shared__ unsigned short As[128 * 64];
  __shared__ unsigned short Bs[128 * 64];
  const int K = 256;
  const int tid  = threadIdx.x;
  const int lane = tid & 63;
  const int wid  = tid >> 6;
  const int wm   = wid >> 2;
  const int wn   = wid & 3;

  const int chunk = gridDim.x >> 3;            // 128
  const int l     = (blockIdx.x & 7) * chunk + (blockIdx.x >> 3);
  const bool isK  = (l < 512);
  const int  ll   = isK ? l : l - 512;
  const int  nx   = isK ? 8 : 64;
  const unsigned short* A  = isK ? kv : Wv;
  const unsigned short* Bw = isK ? Wk : kv;
  unsigned short* C        = isK ? Ck : Cvt;
  const int Nout           = isK ? 1024 : 8192;
  const int n0    = (ll % nx) * 128;
  const int m0    = (ll / nx) * 128;

  f32x4 acc[4][2] = {};

  const int prow = tid >> 3;
  const int pblk = (tid & 7) ^ (prow & 7);
  const int le   = tid * 8;

  const int g = lane >> 4;
  const int m = lane & 15;
  const int s7 = lane & 7;

  for (int kt = 0; kt < K; kt += 64) {
#pragma unroll
    for (int p = 0; p < 2; ++p)
      gl_lds16(A  + (size_t)(m0 + p * 64 + prow) * K + kt + pblk * 8, &As[p * 4096 + le]);
#pragma unroll
    for (int p = 0; p < 2; ++p)
      gl_lds16(Bw + (size_t)(n0 + p * 64 + prow) * K + kt + pblk * 8, &Bs[p * 4096 + le]);
    __syncthreads();

#pragma unroll
    for (int c = 0; c < 2; ++c) {
      const int blk = (c * 4 + g) ^ s7;
      bf16x8 af[4], bfr[2];
#pragma unroll
      for (int i = 0; i < 4; ++i) {
        const int row = wm * 64 + i * 16 + m;
        af[i] = *(const bf16x8*)&As[row * 64 + blk * 8];
      }
#pragma unroll
      for (int j = 0; j < 2; ++j) {
        const int row = wn * 32 + j * 16 + m;
        bfr[j] = *(const bf16x8*)&Bs[row * 64 + blk * 8];
      }
#pragma unroll
      for (int i = 0; i < 4; ++i)
#pragma unroll
        for (int j = 0; j < 2; ++j)
          acc[i][j] = __builtin_amdgcn_mfma_f32_16x16x32_bf16(af[i], bfr[j], acc[i][j], 0, 0, 0);
    }
    __syncthreads();
  }

  const int r0 = m0 + wm * 64 + ((lane >> 4) * 4);
  const int c0 = n0 + wn * 32 + m;
  if (isK) {
#pragma unroll
    for (int j = 0; j < 2; ++j) {
      float bj = bk[c0 + j * 16];
#pragma unroll
      for (int i = 0; i < 4; ++i)
#pragma unroll
        for (int r = 0; r < 4; ++r)
          C[(size_t)(r0 + i * 16 + r) * Nout + (c0 + j * 16)] = f2bf(acc[i][j][r] + bj);
    }
  } else {
#pragma unroll
    for (int i = 0; i < 4; ++i)
#pragma unroll
      for (int r = 0; r < 4; ++r) {
        float br = bv[r0 + i * 16 + r];
#pragma unroll
        for (int j = 0; j < 2; ++j)
          C[(size_t)(r0 + i * 16 + r) * Nout + (c0 + j * 16)] = f2bf(acc[i][j][r] + br);
      }
  }
}

// ---------------- flash attention: 8-wave blocks, KV tile 256, T15 double-pipeline ----------------
__global__ __launch_bounds__(512)
void k_flash(const unsigned short* __restrict__ Q,
             const unsigned short* __restrict__ Kg,
             const unsigned short* __restrict__ Vt,
             unsigned short* __restrict__ O) {
  __shared__ unsigned short Ks[256 * 64];  // 32 KB, [k][d], 16B-block XOR-swizzled by row&7
  __shared__ unsigned short Vs[64 * 256];  // 32 KB, [d][k], swizzled
  const int tid  = threadIdx.x;
  const int lane = tid & 63;
  const int wid  = tid >> 6;               // 0..7
  // XCD swizzle: 512 blocks = 8 XCDs x 64
  const int bid     = blockIdx.x;
  const int logical = (bid & 7) * 64 + (bid >> 3);
  const int bh      = logical >> 3;        // 0..63
  const int qt      = logical & 7;         // 0..7
  const int b   = bh >> 4, h = bh & 15;
  const int hi  = lane >> 5;               // 0/1
  const int q   = lane & 31;               // q-row (and d-col for PV)
  const int sw  = lane & 7;
  const int q0  = qt * 256 + wid * 32;     // wave q-base

  bf16x8 qf[4];
  {
    const unsigned short* qp = Q + (size_t)(b * N_ + q0 + q) * D_ + h * 64 + hi * 8;
    qf[0] = *(const bf16x8*)qp;
    qf[1] = *(const bf16x8*)(qp + 16);
    qf[2] = *(const bf16x8*)(qp + 32);
    qf[3] = *(const bf16x8*)(qp + 48);
  }

  union { unsigned short s[8]; bf16x8 v; } one_u;
#pragma unroll
  for (int i = 0; i < 8; ++i) one_u.s[i] = 0x3F80;

  f32x16 o0 = {0.f}, o1 = {0.f};
  f32x16 acc_l = {0.f};
  f32x16 sa0[2], sa1[2];     // double-buffered S-tiles (static after full unroll)

  for (int kv0 = 0; kv0 < N_; kv0 += 256) {
#pragma unroll
    for (int p = 0; p < 4; ++p) {
      int r   = p * 64 + (tid >> 3);
      int blk = (tid & 7) ^ (r & 7);
      gl_lds16(Kg + (size_t)(b * N_ + kv0 + r) * D_ + h * 64 + blk * 8, &Ks[p * 4096 + tid * 8]);
    }
#pragma unroll
    for (int p = 0; p < 4; ++p) {
      int r   = p * 16 + (tid >> 5);
      int blk = (tid & 31) ^ (r & 7);
      gl_lds16(Vt + (size_t)(h * 64 + r) * (B_ * N_) + b * N_ + kv0 + blk * 8,
               &Vs[p * 4096 + tid * 8]);
    }
    __syncthreads();

    // prologue: QK^T for st2=0
    {
      f32x16 a0 = {0.f}, a1 = {0.f};
      const unsigned short* Kb = &Ks[0];
      __builtin_amdgcn_s_setprio(1);
#pragma unroll
      for (int c4 = 0; c4 < 4; ++c4) {
        const int blk = ((c4 * 2 + hi) ^ sw) * 8;
        a0 = __builtin_amdgcn_mfma_f32_32x32x16_bf16(*(const bf16x8*)&Kb[q * 64 + blk], qf[c4], a0, 0, 0, 0);
        a1 = __builtin_amdgcn_mfma_f32_32x32x16_bf16(*(const bf16x8*)&Kb[(32 + q) * 64 + blk], qf[c4], a1, 0, 0, 0);
      }
      __builtin_amdgcn_s_setprio(0);
      sa0[0] = a0; sa1[0] = a1;
    }

#pragma unroll
    for (int st2 = 0; st2 < 4; ++st2) {
      // issue next sub-tile's QK^T before this sub-tile's softmax (T15 overlap)
      if (st2 < 3) {
        const int nb_ = (st2 + 1) & 1;
        f32x16 a0 = {0.f}, a1 = {0.f};
        const unsigned short* Kb = &Ks[(st2 + 1) * 64 * 64];
        __builtin_amdgcn_s_setprio(1);
#pragma unroll
        for (int c4 = 0; c4 < 4; ++c4) {
          const int blk = ((c4 * 2 + hi) ^ sw) * 8;
          a0 = __builtin_amdgcn_mfma_f32_32x32x16_bf16(*(const bf16x8*)&Kb[q * 64 + blk], qf[c4], a0, 0, 0, 0);
          a1 = __builtin_amdgcn_mfma_f32_32x32x16_bf16(*(const bf16x8*)&Kb[(32 + q) * 64 + blk], qf[c4], a1, 0, 0, 0);
        }
        __builtin_amdgcn_s_setprio(0);
        sa0[nb_] = a0; sa1[nb_] = a1;
      }

      const int cb = st2 & 1;
#pragma unroll
      for (int st = 0; st < 2; ++st) {
        float p[16];
#pragma unroll
        for (int r = 0; r < 16; ++r) {
          float sv = st ? sa1[cb][r] : sa0[cb][r];
          p[r] = fexp2(sv);
        }
        unsigned int w0 = pk2(p[0],  p[1]),  w1 = pk2(p[2],  p[3]);
        unsigned int w2 = pk2(p[4],  p[5]),  w3 = pk2(p[6],  p[7]);
        unsigned int w4 = pk2(p[8],  p[9]),  w5 = pk2(p[10], p[11]);
        unsigned int w6 = pk2(p[12], p[13]), w7 = pk2(p[14], p[15]);
        auto r02 = __builtin_amdgcn_permlane32_swap(w0, w2, false, false);
        auto r13 = __builtin_amdgcn_permlane32_swap(w1, w3, false, false);
        auto r46 = __builtin_amdgcn_permlane32_swap(w4, w6, false, false);
        auto r57 = __builtin_amdgcn_permlane32_swap(w5, w7, false, false);
        union { unsigned int u[4]; bf16x8 v; } fA, fB;
        fA.u[0] = r02[0]; fA.u[1] = r13[0]; fA.u[2] = r02[1]; fA.u[3] = r13[1];
        fB.u[0] = r46[0]; fB.u[1] = r57[0]; fB.u[2] = r46[1]; fB.u[3] = r57[1];

        {
          const int blkA = ((st2 * 8 + st * 4 + 0 + hi) ^ sw) * 8;
          const int blkB = ((st2 * 8 + st * 4 + 2 + hi) ^ sw) * 8;
          bf16x8 v00 = *(const bf16x8*)&Vs[q * 256 + blkA];
          bf16x8 v01 = *(const bf16x8*)&Vs[q * 256 + blkB];
          bf16x8 v10 = *(const bf16x8*)&Vs[(32 + q) * 256 + blkA];
          bf16x8 v11 = *(const bf16x8*)&Vs[(32 + q) * 256 + blkB];
          __builtin_amdgcn_s_setprio(1);
          o0 = __builtin_amdgcn_mfma_f32_32x32x16_bf16(fA.v, v00, o0, 0, 0, 0);
          o0 = __builtin_amdgcn_mfma_f32_32x32x16_bf16(fB.v, v01, o0, 0, 0, 0);
          o1 = __builtin_amdgcn_mfma_f32_32x32x16_bf16(fA.v, v10, o1, 0, 0, 0);
          o1 = __builtin_amdgcn_mfma_f32_32x32x16_bf16(fB.v, v11, o1, 0, 0, 0);
          acc_l = __builtin_amdgcn_mfma_f32_32x32x16_bf16(fA.v, one_u.v, acc_l, 0, 0, 0);
          acc_l = __builtin_amdgcn_mfma_f32_32x32x16_bf16(fB.v, one_u.v, acc_l, 0, 0, 0);
          __builtin_amdgcn_s_setprio(0);
        }
      }
    }
    __syncthreads();
  }

#pragma unroll
  for (int r2 = 0; r2 < 16; ++r2) {
    const int qp_ = (r2 & 3) + 8 * (r2 >> 2);
    float li = 1.0f / acc_l[r2];
    const int qq = q0 + qp_ + hi * 4;
    unsigned short* op = O + (size_t)(b * N_ + qq) * D_ + h * 64 + q;
    op[0]  = f2bf(o0[r2] * li);
    op[32] = f2bf(o1[r2] * li);
  }
}

extern "C" void kernel_launch(void* const* d_in, const int* in_sizes, int n_in,
                              void* d_out, int out_size, void* d_ws, size_t ws_size,
                              hipStream_t stream) {
  const float* x  = (const float*)d_in[0];
  const float* Wq = (const float*)d_in[1];
  const float* bq = (const float*)d_in[2];
  const float* Wd = (const float*)d_in[3];
  const float* bd = (const float*)d_in[4];
  const float* Wk = (const float*)d_in[5];
  const float* bk = (const float*)d_in[6];
  const float* Wv = (const float*)d_in[7];
  const float* bv = (const float*)d_in[8];
  const float* Wo = (const float*)d_in[9];
  const float* bo = (const float*)d_in[10];
  float* out = (float*)d_out;

  unsigned short* ws  = (unsigned short*)d_ws;
  unsigned short* xb  = ws;                  // 8388608  (x bf16, reused as attn-out)
  unsigned short* qb  = xb  + 8388608;       // 8388608
  unsigned short* kvb = qb  + 8388608;       // 2097152
  unsigned short* kb  = kvb + 2097152;       // 8388608
  unsigned short* vb  = kb  + 8388608;       // 8388608 (unused)
  unsigned short* vtb = vb  + 8388608;       // 8388608 (v^T: [h*64+d][b*2048+n])
  unsigned short* Wqb = vtb + 8388608;       // 1048576
  unsigned short* Wdb = Wqb + 1048576;       // 262144
  unsigned short* Wkb = Wdb + 262144;        // 262144
  unsigned short* Wvb = Wkb + 262144;        // 262144
  unsigned short* Wob = Wvb + 262144;        // 1048576
  unsigned short* aob = xb;                  // reuse: x dead after qkv GEMM

  const float cs = 0.125f * 1.44269504088896f;  // attn scale * log2(e), folded into q

  k_cvt_all<<<dim3(11008), dim3(256), 0, stream>>>(x, Wq, Wd, Wk, Wv, Wo,
                                                   xb, Wqb, Wdb, Wkb, Wvb, Wob);

  // fused q + kv_latent GEMM (N=1280 logical; grid 640 = 8 x 80, nx=10)
  k_gemm_qkv<<<dim3(640), dim3(512), 0, stream>>>(xb, Wqb, Wdb, bq, bd, qb, kvb, cs);
  // fused k + v^T GEMM (1024 blocks; k tiles 0-511, vT tiles 512-1023)
  k_gemm_kv<<<dim3(1024), dim3(512), 0, stream>>>(kvb, Wkb, bk, kb, Wvb, bv, vtb);
  k_flash<<<dim3(512), dim3(512), 0, stream>>>(qb, kb, vtb, aob);
  k_gemm_bt<float, false><<<dim3(512), dim3(512), 0, stream>>>(aob, Wob, bo, out, 8192, 1024, 1024, 1.0f, 8);
}

// Round 18
// 174.962 us; speedup vs baseline: 1.0084x; 1.0084x over previous
//
#include <hip/hip_runtime.h>
#include <hip/hip_bf16.h>

#define D_    1024
#define H_    16
#define HD_   64
#define RANK_ 256
#define B_    4
#define N_    2048

typedef __attribute__((ext_vector_type(8))) short bf16x8;
typedef __attribute__((ext_vector_type(4))) float f32x4;
typedef __attribute__((ext_vector_type(16))) float f32x16;
typedef __attribute__((ext_vector_type(8))) unsigned short u16x8;

__device__ __forceinline__ unsigned short f2bf(float f) {
  unsigned int u = __float_as_uint(f);
  u += 0x7FFF + ((u >> 16) & 1);   // round-to-nearest-even
  return (unsigned short)(u >> 16);
}

__device__ __forceinline__ unsigned int pk2(float a, float b) {
  float2 t; t.x = a; t.y = b;
  __hip_bfloat162 h = __float22bfloat162_rn(t);
  union { __hip_bfloat162 h; unsigned int u; } cv; cv.h = h; return cv.u;
}

// raw v_exp_f32 (2^x): args bounded, skip the OCML range-checked routine
__device__ __forceinline__ float fexp2(float x) {
#if __has_builtin(__builtin_amdgcn_exp2f)
  return __builtin_amdgcn_exp2f(x);
#else
  return exp2f(x);
#endif
}

__device__ __forceinline__ void gl_lds16(const void* g, void* l) {
  __builtin_amdgcn_global_load_lds(
      (const __attribute__((address_space(1))) unsigned int*)g,
      (__attribute__((address_space(3))) unsigned int*)l,
      16, 0, 0);
}

// ---------------- fused fp32 -> bf16 convert: x + 5 weight matrices ----------------
// float4 segments: x 2097152 | Wq 262144 | Wd 65536 | Wk 65536 | Wv 65536 | Wo 262144
__global__ __launch_bounds__(256)
void k_cvt_all(const float* __restrict__ x,
               const float* __restrict__ w0, const float* __restrict__ w1,
               const float* __restrict__ w2, const float* __restrict__ w3,
               const float* __restrict__ w4,
               unsigned short* __restrict__ ox,
               unsigned short* __restrict__ o0, unsigned short* __restrict__ o1,
               unsigned short* __restrict__ o2, unsigned short* __restrict__ o3,
               unsigned short* __restrict__ o4) {
  int i = blockIdx.x * 256 + threadIdx.x;
  const float* in; unsigned short* out; int off;
  if (i < 2097152)      { in = x;  out = ox; off = i; }
  else if (i < 2359296) { in = w0; out = o0; off = i - 2097152; }
  else if (i < 2424832) { in = w1; out = o1; off = i - 2359296; }
  else if (i < 2490368) { in = w2; out = o2; off = i - 2424832; }
  else if (i < 2555904) { in = w3; out = o3; off = i - 2490368; }
  else                  { in = w4; out = o4; off = i - 2555904; }
  float4 v = ((const float4*)in)[off];
  union { unsigned short s[4]; unsigned long long u; } r;
  r.s[0] = f2bf(v.x); r.s[1] = f2bf(v.y); r.s[2] = f2bf(v.z); r.s[3] = f2bf(v.w);
  ((unsigned long long*)out)[off] = r.u;
}

// ---------------- GEMM: C[M,N] = (A[M,K] * W[N,K]^T + bias) * scale ----------------
// 8 waves (512 thr), 128x128 tile, per-wave 64x32 output (wm=wid>>2, wn=wid&3).
// BK=64, XOR-swizzled LDS, bijective XCD-swizzled 1-D grid (gridDim.x % 8 == 0).
__device__ __forceinline__ void storeC(float* C, size_t idx, float v) { C[idx] = v; }
__device__ __forceinline__ void storeC(unsigned short* C, size_t idx, float v) { C[idx] = f2bf(v); }

template<typename OUT_T, bool BROW>
__global__ __launch_bounds__(512)
void k_gemm_bt(const unsigned short* __restrict__ A,
               const unsigned short* __restrict__ Bw,
               const float* __restrict__ bias,
               OUT_T* __restrict__ C,
               int M, int N, int K, float scale, int nx) {
  __shared__ unsigned short As[128 * 64];
  __shared__ unsigned short Bs[128 * 64];
  const int tid  = threadIdx.x;
  const int lane = tid & 63;
  const int wid  = tid >> 6;
  const int wm   = wid >> 2;
  const int wn   = wid & 3;

  const int nb    = gridDim.x;
  const int chunk = nb >> 3;
  const int l     = (blockIdx.x & 7) * chunk + (blockIdx.x >> 3);
  const int n0    = (l % nx) * 128;
  const int m0    = (l / nx) * 128;

  f32x4 acc[4][2] = {};

  const int prow = tid >> 3;
  const int pblk = (tid & 7) ^ (prow & 7);
  const int le   = tid * 8;

  const int g = lane >> 4;
  const int m = lane & 15;
  const int s7 = lane & 7;

  for (int kt = 0; kt < K; kt += 64) {
#pragma unroll
    for (int p = 0; p < 2; ++p)
      gl_lds16(A  + (size_t)(m0 + p * 64 + prow) * K + kt + pblk * 8, &As[p * 4096 + le]);
#pragma unroll
    for (int p = 0; p < 2; ++p)
      gl_lds16(Bw + (size_t)(n0 + p * 64 + prow) * K + kt + pblk * 8, &Bs[p * 4096 + le]);
    __syncthreads();

#pragma unroll
    for (int c = 0; c < 2; ++c) {
      const int blk = (c * 4 + g) ^ s7;
      bf16x8 af[4], bfr[2];
#pragma unroll
      for (int i = 0; i < 4; ++i) {
        const int row = wm * 64 + i * 16 + m;
        af[i] = *(const bf16x8*)&As[row * 64 + blk * 8];
      }
#pragma unroll
      for (int j = 0; j < 2; ++j) {
        const int row = wn * 32 + j * 16 + m;
        bfr[j] = *(const bf16x8*)&Bs[row * 64 + blk * 8];
      }
#pragma unroll
      for (int i = 0; i < 4; ++i)
#pragma unroll
        for (int j = 0; j < 2; ++j)
          acc[i][j] = __builtin_amdgcn_mfma_f32_16x16x32_bf16(af[i], bfr[j], acc[i][j], 0, 0, 0);
    }
    __syncthreads();
  }

  const int r0 = m0 + wm * 64 + ((lane >> 4) * 4);
  const int c0 = n0 + wn * 32 + m;
  if constexpr (BROW) {
#pragma unroll
    for (int i = 0; i < 4; ++i)
#pragma unroll
      for (int r = 0; r < 4; ++r) {
        float br = bias[r0 + i * 16 + r];
#pragma unroll
        for (int j = 0; j < 2; ++j) {
          float v = (acc[i][j][r] + br) * scale;
          storeC(C, (size_t)(r0 + i * 16 + r) * N + (c0 + j * 16), v);
        }
      }
  } else {
#pragma unroll
    for (int j = 0; j < 2; ++j) {
      float bj = bias[c0 + j * 16];
#pragma unroll
      for (int i = 0; i < 4; ++i)
#pragma unroll
        for (int r = 0; r < 4; ++r) {
          float v = (acc[i][j][r] + bj) * scale;
          storeC(C, (size_t)(r0 + i * 16 + r) * N + (c0 + j * 16), v);
        }
    }
  }
}

// ---------------- fused q+kv GEMM: [q | kv_latent] = x @ [Wq ; Wd]^T ----------------
__global__ __launch_bounds__(512)
void k_gemm_qkv(const unsigned short* __restrict__ A,
                const unsigned short* __restrict__ Wq,
                const unsigned short* __restrict__ Wd,
                const float* __restrict__ bq,
                const float* __restrict__ bd,
                unsigned short* __restrict__ Cq,
                unsigned short* __restrict__ Ckv,
                float cs) {
  __shared__ unsigned short As[128 * 64];
  __shared__ unsigned short Bs[128 * 64];
  const int K = 1024;
  const int tid  = threadIdx.x;
  const int lane = tid & 63;
  const int wid  = tid >> 6;
  const int wm   = wid >> 2;
  const int wn   = wid & 3;

  const int chunk = gridDim.x >> 3;            // 80
  const int l     = (blockIdx.x & 7) * chunk + (blockIdx.x >> 3);
  const int n0    = (l % 10) * 128;
  const int m0    = (l / 10) * 128;

  const bool isQ = (n0 < 1024);
  const unsigned short* Bw = isQ ? Wq : Wd;
  const float* bias        = isQ ? bq : bd;
  unsigned short* C        = isQ ? Cq : Ckv;
  const float scale        = isQ ? cs : 1.0f;
  const int Nout           = isQ ? 1024 : 256;
  const int nb0            = isQ ? n0 : n0 - 1024;

  f32x4 acc[4][2] = {};

  const int prow = tid >> 3;
  const int pblk = (tid & 7) ^ (prow & 7);
  const int le   = tid * 8;

  const int g = lane >> 4;
  const int m = lane & 15;
  const int s7 = lane & 7;

  for (int kt = 0; kt < K; kt += 64) {
#pragma unroll
    for (int p = 0; p < 2; ++p)
      gl_lds16(A  + (size_t)(m0 + p * 64 + prow) * K + kt + pblk * 8, &As[p * 4096 + le]);
#pragma unroll
    for (int p = 0; p < 2; ++p)
      gl_lds16(Bw + (size_t)(nb0 + p * 64 + prow) * K + kt + pblk * 8, &Bs[p * 4096 + le]);
    __syncthreads();

#pragma unroll
    for (int c = 0; c < 2; ++c) {
      const int blk = (c * 4 + g) ^ s7;
      bf16x8 af[4], bfr[2];
#pragma unroll
      for (int i = 0; i < 4; ++i) {
        const int row = wm * 64 + i * 16 + m;
        af[i] = *(const bf16x8*)&As[row * 64 + blk * 8];
      }
#pragma unroll
      for (int j = 0; j < 2; ++j) {
        const int row = wn * 32 + j * 16 + m;
        bfr[j] = *(const bf16x8*)&Bs[row * 64 + blk * 8];
      }
#pragma unroll
      for (int i = 0; i < 4; ++i)
#pragma unroll
        for (int j = 0; j < 2; ++j)
          acc[i][j] = __builtin_amdgcn_mfma_f32_16x16x32_bf16(af[i], bfr[j], acc[i][j], 0, 0, 0);
    }
    __syncthreads();
  }

  const int r0 = m0 + wm * 64 + ((lane >> 4) * 4);
  const int c0 = nb0 + wn * 32 + m;
#pragma unroll
  for (int j = 0; j < 2; ++j) {
    float bj = bias[c0 + j * 16];
#pragma unroll
    for (int i = 0; i < 4; ++i)
#pragma unroll
      for (int r = 0; r < 4; ++r) {
        float v = (acc[i][j][r] + bj) * scale;
        C[(size_t)(r0 + i * 16 + r) * Nout + (c0 + j * 16)] = f2bf(v);
      }
  }
}

// ---------------- flash attention: 8-wave blocks, KV tile 256, T15 double-pipeline ----------------
__global__ __launch_bounds__(512)
void k_flash(const unsigned short* __restrict__ Q,
             const unsigned short* __restrict__ Kg,
             const unsigned short* __restrict__ Vt,
             unsigned short* __restrict__ O) {
  __shared__ unsigned short Ks[256 * 64];  // 32 KB, [k][d], 16B-block XOR-swizzled by row&7
  __shared__ unsigned short Vs[64 * 256];  // 32 KB, [d][k], swizzled
  const int tid  = threadIdx.x;
  const int lane = tid & 63;
  const int wid  = tid >> 6;               // 0..7
  // XCD swizzle: 512 blocks = 8 XCDs x 64
  const int bid     = blockIdx.x;
  const int logical = (bid & 7) * 64 + (bid >> 3);
  const int bh      = logical >> 3;        // 0..63
  const int qt      = logical & 7;         // 0..7
  const int b   = bh >> 4, h = bh & 15;
  const int hi  = lane >> 5;               // 0/1
  const int q   = lane & 31;               // q-row (and d-col for PV)
  const int sw  = lane & 7;
  const int q0  = qt * 256 + wid * 32;     // wave q-base

  bf16x8 qf[4];
  {
    const unsigned short* qp = Q + (size_t)(b * N_ + q0 + q) * D_ + h * 64 + hi * 8;
    qf[0] = *(const bf16x8*)qp;
    qf[1] = *(const bf16x8*)(qp + 16);
    qf[2] = *(const bf16x8*)(qp + 32);
    qf[3] = *(const bf16x8*)(qp + 48);
  }

  union { unsigned short s[8]; bf16x8 v; } one_u;
#pragma unroll
  for (int i = 0; i < 8; ++i) one_u.s[i] = 0x3F80;

  f32x16 o0 = {0.f}, o1 = {0.f};
  f32x16 acc_l = {0.f};
  f32x16 sa0[2], sa1[2];     // double-buffered S-tiles (static after full unroll)

  for (int kv0 = 0; kv0 < N_; kv0 += 256) {
#pragma unroll
    for (int p = 0; p < 4; ++p) {
      int r   = p * 64 + (tid >> 3);
      int blk = (tid & 7) ^ (r & 7);
      gl_lds16(Kg + (size_t)(b * N_ + kv0 + r) * D_ + h * 64 + blk * 8, &Ks[p * 4096 + tid * 8]);
    }
#pragma unroll
    for (int p = 0; p < 4; ++p) {
      int r   = p * 16 + (tid >> 5);
      int blk = (tid & 31) ^ (r & 7);
      gl_lds16(Vt + (size_t)(h * 64 + r) * (B_ * N_) + b * N_ + kv0 + blk * 8,
               &Vs[p * 4096 + tid * 8]);
    }
    __syncthreads();

    // prologue: QK^T for st2=0
    {
      f32x16 a0 = {0.f}, a1 = {0.f};
      const unsigned short* Kb = &Ks[0];
      __builtin_amdgcn_s_setprio(1);
#pragma unroll
      for (int c4 = 0; c4 < 4; ++c4) {
        const int blk = ((c4 * 2 + hi) ^ sw) * 8;
        a0 = __builtin_amdgcn_mfma_f32_32x32x16_bf16(*(const bf16x8*)&Kb[q * 64 + blk], qf[c4], a0, 0, 0, 0);
        a1 = __builtin_amdgcn_mfma_f32_32x32x16_bf16(*(const bf16x8*)&Kb[(32 + q) * 64 + blk], qf[c4], a1, 0, 0, 0);
      }
      __builtin_amdgcn_s_setprio(0);
      sa0[0] = a0; sa1[0] = a1;
    }

#pragma unroll
    for (int st2 = 0; st2 < 4; ++st2) {
      // issue next sub-tile's QK^T before this sub-tile's softmax (T15 overlap)
      if (st2 < 3) {
        const int nb_ = (st2 + 1) & 1;
        f32x16 a0 = {0.f}, a1 = {0.f};
        const unsigned short* Kb = &Ks[(st2 + 1) * 64 * 64];
        __builtin_amdgcn_s_setprio(1);
#pragma unroll
        for (int c4 = 0; c4 < 4; ++c4) {
          const int blk = ((c4 * 2 + hi) ^ sw) * 8;
          a0 = __builtin_amdgcn_mfma_f32_32x32x16_bf16(*(const bf16x8*)&Kb[q * 64 + blk], qf[c4], a0, 0, 0, 0);
          a1 = __builtin_amdgcn_mfma_f32_32x32x16_bf16(*(const bf16x8*)&Kb[(32 + q) * 64 + blk], qf[c4], a1, 0, 0, 0);
        }
        __builtin_amdgcn_s_setprio(0);
        sa0[nb_] = a0; sa1[nb_] = a1;
      }

      const int cb = st2 & 1;
#pragma unroll
      for (int st = 0; st < 2; ++st) {
        float p[16];
#pragma unroll
        for (int r = 0; r < 16; ++r) {
          float sv = st ? sa1[cb][r] : sa0[cb][r];
          p[r] = fexp2(sv);
        }
        unsigned int w0 = pk2(p[0],  p[1]),  w1 = pk2(p[2],  p[3]);
        unsigned int w2 = pk2(p[4],  p[5]),  w3 = pk2(p[6],  p[7]);
        unsigned int w4 = pk2(p[8],  p[9]),  w5 = pk2(p[10], p[11]);
        unsigned int w6 = pk2(p[12], p[13]), w7 = pk2(p[14], p[15]);
        auto r02 = __builtin_amdgcn_permlane32_swap(w0, w2, false, false);
        auto r13 = __builtin_amdgcn_permlane32_swap(w1, w3, false, false);
        auto r46 = __builtin_amdgcn_permlane32_swap(w4, w6, false, false);
        auto r57 = __builtin_amdgcn_permlane32_swap(w5, w7, false, false);
        union { unsigned int u[4]; bf16x8 v; } fA, fB;
        fA.u[0] = r02[0]; fA.u[1] = r13[0]; fA.u[2] = r02[1]; fA.u[3] = r13[1];
        fB.u[0] = r46[0]; fB.u[1] = r57[0]; fB.u[2] = r46[1]; fB.u[3] = r57[1];

        {
          const int blkA = ((st2 * 8 + st * 4 + 0 + hi) ^ sw) * 8;
          const int blkB = ((st2 * 8 + st * 4 + 2 + hi) ^ sw) * 8;
          bf16x8 v00 = *(const bf16x8*)&Vs[q * 256 + blkA];
          bf16x8 v01 = *(const bf16x8*)&Vs[q * 256 + blkB];
          bf16x8 v10 = *(const bf16x8*)&Vs[(32 + q) * 256 + blkA];
          bf16x8 v11 = *(const bf16x8*)&Vs[(32 + q) * 256 + blkB];
          __builtin_amdgcn_s_setprio(1);
          o0 = __builtin_amdgcn_mfma_f32_32x32x16_bf16(fA.v, v00, o0, 0, 0, 0);
          o0 = __builtin_amdgcn_mfma_f32_32x32x16_bf16(fB.v, v01, o0, 0, 0, 0);
          o1 = __builtin_amdgcn_mfma_f32_32x32x16_bf16(fA.v, v10, o1, 0, 0, 0);
          o1 = __builtin_amdgcn_mfma_f32_32x32x16_bf16(fB.v, v11, o1, 0, 0, 0);
          acc_l = __builtin_amdgcn_mfma_f32_32x32x16_bf16(fA.v, one_u.v, acc_l, 0, 0, 0);
          acc_l = __builtin_amdgcn_mfma_f32_32x32x16_bf16(fB.v, one_u.v, acc_l, 0, 0, 0);
          __builtin_amdgcn_s_setprio(0);
        }
      }
    }
    __syncthreads();
  }

#pragma unroll
  for (int r2 = 0; r2 < 16; ++r2) {
    const int qp_ = (r2 & 3) + 8 * (r2 >> 2);
    float li = 1.0f / acc_l[r2];
    const int qq = q0 + qp_ + hi * 4;
    unsigned short* op = O + (size_t)(b * N_ + qq) * D_ + h * 64 + q;
    op[0]  = f2bf(o0[r2] * li);
    op[32] = f2bf(o1[r2] * li);
  }
}

extern "C" void kernel_launch(void* const* d_in, const int* in_sizes, int n_in,
                              void* d_out, int out_size, void* d_ws, size_t ws_size,
                              hipStream_t stream) {
  const float* x  = (const float*)d_in[0];
  const float* Wq = (const float*)d_in[1];
  const float* bq = (const float*)d_in[2];
  const float* Wd = (const float*)d_in[3];
  const float* bd = (const float*)d_in[4];
  const float* Wk = (const float*)d_in[5];
  const float* bk = (const float*)d_in[6];
  const float* Wv = (const float*)d_in[7];
  const float* bv = (const float*)d_in[8];
  const float* Wo = (const float*)d_in[9];
  const float* bo = (const float*)d_in[10];
  float* out = (float*)d_out;

  unsigned short* ws  = (unsigned short*)d_ws;
  unsigned short* xb  = ws;                  // 8388608  (x bf16, reused as attn-out)
  unsigned short* qb  = xb  + 8388608;       // 8388608
  unsigned short* kvb = qb  + 8388608;       // 2097152
  unsigned short* kb  = kvb + 2097152;       // 8388608
  unsigned short* vb  = kb  + 8388608;       // 8388608 (unused)
  unsigned short* vtb = vb  + 8388608;       // 8388608 (v^T: [h*64+d][b*2048+n])
  unsigned short* Wqb = vtb + 8388608;       // 1048576
  unsigned short* Wdb = Wqb + 1048576;       // 262144
  unsigned short* Wkb = Wdb + 262144;        // 262144
  unsigned short* Wvb = Wkb + 262144;        // 262144
  unsigned short* Wob = Wvb + 262144;        // 1048576
  unsigned short* aob = xb;                  // reuse: x dead after qkv GEMM

  const float cs = 0.125f * 1.44269504088896f;  // attn scale * log2(e), folded into q

  k_cvt_all<<<dim3(11008), dim3(256), 0, stream>>>(x, Wq, Wd, Wk, Wv, Wo,
                                                   xb, Wqb, Wdb, Wkb, Wvb, Wob);

  // fused q + kv_latent GEMM (N=1280 logical; grid 640 = 8 x 80, nx=10)
  k_gemm_qkv<<<dim3(640), dim3(512), 0, stream>>>(xb, Wqb, Wdb, bq, bd, qb, kvb, cs);
  k_gemm_bt<unsigned short, false><<<dim3(512), dim3(512), 0, stream>>>(kvb, Wkb, bk, kb,  8192, 1024,  256, 1.0f, 8);
  // v^T = Wv @ kv^T + bv (row bias): C [1024, 8192] in [h*64+d][b*2048+n] layout
  k_gemm_bt<unsigned short, true><<<dim3(512), dim3(512), 0, stream>>>(Wvb, kvb, bv, vtb, 1024, 8192,  256, 1.0f, 64);
  k_flash<<<dim3(512), dim3(512), 0, stream>>>(qb, kb, vtb, aob);
  k_gemm_bt<float, false><<<dim3(512), dim3(512), 0, stream>>>(aob, Wob, bo, out, 8192, 1024, 1024, 1.0f, 8);
}